// Round 6
// baseline (703.416 us; speedup 1.0000x reference)
//
#include <hip/hip_runtime.h>
#include <cstdint>

#define B_SZ 4096
#define T_SZ 1000
#define I_SZ 3
#define H_SZ 10
// Row-split decomposition: lane = (grp, gate, unit). 30 lanes per batch element
// (3 gates x 10 units), 2 real groups per wave, lanes 60-63 idle-ish (grp 2,
// reads zeroed LDS, never writes). Per-lane weights: 53 floats -> register-
// resident by construction (R4/R5 lesson: RA refuses to keep 159/lane live).

__device__ __forceinline__ float fsig(float s) {
    float e = __expf(-s);                       // s<<0 -> inf -> rcp 0; s>>0 -> 1
    return __builtin_amdgcn_rcpf(1.0f + e);
}
__device__ __forceinline__ float ftanh(float y) {
    float e2 = __expf(y + y);                   // inf-safe both ends
    return 1.0f - 2.0f * __builtin_amdgcn_rcpf(e2 + 1.0f);
}

// unpack 3 float4 (10 used) into named scalars dst0..dst9
#define U10(dst, q0, q1, q2) \
    const float dst##0=(q0).x, dst##1=(q0).y, dst##2=(q0).z, dst##3=(q0).w, \
                dst##4=(q1).x, dst##5=(q1).y, dst##6=(q1).z, dst##7=(q1).w, \
                dst##8=(q2).x, dst##9=(q2).y;

// one k-step: 5 independent FMAs (5 disjoint accumulator chains, depth 10 each)
#define K5(k) \
    h0a = fmaf(wh0[k], a##k, h0a); \
    i1a = fmaf(wi1[k], a##k, i1a); \
    h1a = fmaf(wh1[k], b##k, h1a); \
    i2a = fmaf(wi2[k], b##k, i2a); \
    h2a = fmaf(wh2[k], c##k, h2a);

__global__ __launch_bounds__(64, 2) void gru3_rows(
    const float* __restrict__ x,
    const float* __restrict__ Wih0, const float* __restrict__ Whh0,
    const float* __restrict__ bih0, const float* __restrict__ bhh0,
    const float* __restrict__ Wih1, const float* __restrict__ Whh1,
    const float* __restrict__ bih1, const float* __restrict__ bhh1,
    const float* __restrict__ Wih2, const float* __restrict__ Whh2,
    const float* __restrict__ bih2, const float* __restrict__ bhh2,
    const float* __restrict__ Wout, const float* __restrict__ bout,
    float* __restrict__ out)
{
    // [grp][layer][12 words]. Read pattern: per (grp,layer) all 30 lanes read the
    // SAME float4 -> broadcast, no conflicts; 3 grp bases are bank-disjoint.
    __shared__ __align__(16) float lds[3 * 3 * 12];

    const int lane = threadIdx.x;      // block = 1 wave
    const int grp  = lane / 30;        // 0,1 real; 2 = lanes 60-63 (dummy)
    const int lig  = lane % 30;        // lane-in-group: gate*10 + unit
    const int gate = lig / 10;         // 0=r 1=z 2=n
    const int u    = lig % 10;
    const int row  = gate * H_SZ + u;  // row of the 3H-row weight matrices
    const int b_raw = blockIdx.x * 2 + grp;
    const int b     = b_raw < B_SZ ? b_raw : (B_SZ - 1);

    // shuffle sources (static per lane): n-lanes pull r from lane-20, z from lane-10
    const int src_r = (lig >= 20) ? (lane - 20) : lane;
    const int src_z = (lig >= 20) ? (lane - 10) : lane;

    // ---- this lane's rows: 53 weights + 6 biases, register-resident ----
    float wi0[I_SZ], wh0[H_SZ];
    float wi1[H_SZ], wh1[H_SZ];
    float wi2[H_SZ], wh2[H_SZ];
#pragma unroll
    for (int i = 0; i < I_SZ; ++i) wi0[i] = Wih0[row * I_SZ + i];
#pragma unroll
    for (int k = 0; k < H_SZ; ++k) {
        wh0[k] = Whh0[row * H_SZ + k];
        wi1[k] = Wih1[row * H_SZ + k];
        wh1[k] = Whh1[row * H_SZ + k];
        wi2[k] = Wih2[row * H_SZ + k];
        wh2[k] = Whh2[row * H_SZ + k];
    }
    const float bi0 = bih0[row], bh0 = bhh0[row];
    const float bi1 = bih1[row], bh1 = bhh1[row];
    const float bi2 = bih2[row], bh2 = bhh2[row];

    // zero the h slots (lanes 60-63's grp-2 slab stays zero forever -> finite math)
    for (int i = lane; i < 3 * 3 * 12; i += 64) lds[i] = 0.0f;

    float hh0 = 0.0f, hh1 = 0.0f, hh2 = 0.0f;   // h state lives on n-lanes

    const float* xp = x + (size_t)b * (T_SZ * I_SZ);
    float cx0 = xp[0], cx1 = xp[1], cx2 = xp[2];   // x[t] for current iter

    const int gb = grp * 36;
    const float4* pa = reinterpret_cast<const float4*>(&lds[gb]);       // h0
    const float4* pb = reinterpret_cast<const float4*>(&lds[gb + 12]);  // h1
    const float4* pc = reinterpret_cast<const float4*>(&lds[gb + 24]);  // h2

    float4 Aq0 = pa[0], Aq1 = pa[1], Aq2 = pa[2];
    float4 Bq0 = pb[0], Bq1 = pb[1], Bq2 = pb[2];
    float4 Cq0 = pc[0], Cq1 = pc[1], Cq2 = pc[2];

    // Layer-pipelined: iter it -> L0@t=it, L1@t=it-1, L2@t=it-2. Barrier-free
    // (single wave; same-wave DS ordering makes write->tail-read safe).
#pragma unroll 1
    for (int it = 0; it < T_SZ + 2; ++it) {
        U10(a, Aq0, Aq1, Aq2)          // h0(prev)
        U10(b, Bq0, Bq1, Bq2)          // h1(prev)
        U10(c, Cq0, Cq1, Cq2)          // h2(prev)

        const float x0 = cx0, x1 = cx1, x2 = cx2;
        const int tn = (it + 1 < T_SZ) ? it + 1 : (T_SZ - 1);
        cx0 = xp[tn * 3 + 0];          // prefetch next x under this body
        cx1 = xp[tn * 3 + 1];
        cx2 = xp[tn * 3 + 2];

        // ---- 6 accumulator chains (acc_i = bih + Wih.in, acc_h = bhh + Whh.h) ----
        float i0a = bi0, h0a = bh0;
        float i1a = bi1, h1a = bh1;
        float i2a = bi2, h2a = bh2;
        i0a = fmaf(wi0[0], x0, i0a);
        i0a = fmaf(wi0[1], x1, i0a);
        i0a = fmaf(wi0[2], x2, i0a);
        K5(0) K5(1) K5(2) K5(3) K5(4)
        K5(5) K5(6) K5(7) K5(8) K5(9)

        // ---- gates: every lane computes sig of its own row sum ----
        const float s0 = fsig(i0a + h0a);
        const float s1 = fsig(i1a + h1a);
        const float s2 = fsig(i2a + h2a);

        // n-lanes pull r and z (uniform instruction, static sources)
        const float r0 = __shfl(s0, src_r), z0 = __shfl(s0, src_z);
        const float r1 = __shfl(s1, src_r), z1 = __shfl(s1, src_z);
        const float r2 = __shfl(s2, src_r), z2 = __shfl(s2, src_z);

        // n = tanh(xn + r*hn)  (acc_i = xn, acc_h = hn on n-lanes)
        const float n0 = ftanh(fmaf(r0, h0a, i0a));
        const float n1 = ftanh(fmaf(r1, h1a, i1a));
        const float n2 = ftanh(fmaf(r2, h2a, i2a));

        // h' = n + z*(h - n); commit only in the layer's active window
        const float t0 = fmaf(z0, hh0 - n0, n0);
        const float t1 = fmaf(z1, hh1 - n1, n1);
        const float t2 = fmaf(z2, hh2 - n2, n2);
        hh0 = (it < T_SZ)             ? t0 : hh0;
        hh1 = (it >= 1 && it <= T_SZ) ? t1 : hh1;
        hh2 = (it >= 2)               ? t2 : hh2;

        if (lig >= 20) {               // n-lanes own the h state
            lds[gb + u]      = hh0;
            lds[gb + 12 + u] = hh1;
            lds[gb + 24 + u] = hh2;
        }

        // rotate: next iteration's h reads issue under the loop tail
        Aq0 = pa[0]; Aq1 = pa[1]; Aq2 = pa[2];
        Bq0 = pb[0]; Bq1 = pb[1]; Bq2 = pb[2];
        Cq0 = pc[0]; Cq1 = pc[1]; Cq2 = pc[2];
    }

    // ---- output projection: out[b] = h2(T-1) . Wout + bout ----
    if (lig == 0 && grp < 2) {
        const float* hv = &lds[gb + 24];
        float acc = bout[0];
#pragma unroll
        for (int k = 0; k < H_SZ; ++k) acc = fmaf(hv[k], Wout[k], acc);
        out[b_raw] = acc;
    }
}

extern "C" void kernel_launch(void* const* d_in, const int* in_sizes, int n_in,
                              void* d_out, int out_size, void* d_ws, size_t ws_size,
                              hipStream_t stream) {
    const float* x    = (const float*)d_in[0];
    const float* Wih0 = (const float*)d_in[1];
    const float* Whh0 = (const float*)d_in[2];
    const float* bih0 = (const float*)d_in[3];
    const float* bhh0 = (const float*)d_in[4];
    const float* Wih1 = (const float*)d_in[5];
    const float* Whh1 = (const float*)d_in[6];
    const float* bih1 = (const float*)d_in[7];
    const float* bhh1 = (const float*)d_in[8];
    const float* Wih2 = (const float*)d_in[9];
    const float* Whh2 = (const float*)d_in[10];
    const float* bih2 = (const float*)d_in[11];
    const float* bhh2 = (const float*)d_in[12];
    const float* Wout = (const float*)d_in[13];
    const float* bout = (const float*)d_in[14];
    float* out = (float*)d_out;

    const int grid = B_SZ / 2;         // 2048 single-wave blocks -> 2 waves/SIMD
    gru3_rows<<<grid, 64, 0, stream>>>(x, Wih0, Whh0, bih0, bhh0,
                                       Wih1, Whh1, bih1, bhh1,
                                       Wih2, Whh2, bih2, bhh2,
                                       Wout, bout, out);
}